// Round 15
// baseline (236.255 us; speedup 1.0000x reference)
//
#include <hip/hip_runtime.h>
#include <math.h>

#define DIMC 256
#define NHEADS 8
#define HDIM 32
#define CPBH 512
#define BB 2
#define NSEQ 2304
#define TAB 9025
#define TABP 9040                  // padded table stride
#define RTOT (BB*NHEADS*NSEQ)      // 36864
#define SPLITS 4
#define MSP (NSEQ/SPLITS)          // 576 m per split
#define PBS 36                     // pbuf row stride in u16
#define NCHUNK (NSEQ/32)           // 72
#define LOG2E 1.44269504088896340736f

#define IDXP_ELEMS    (NSEQ * NCHUNK * 16)             // 2,654,208
#define IDXP4_BLOCKS  (IDXP_ELEMS / 1024)              // 2592
#define CPB_BLOCKS    ((TAB + 63) / 64)                // 142
#define QKV_BLOCKS    (12 * 72)                        // 864

typedef unsigned short ushort;
typedef __attribute__((ext_vector_type(8))) short short8;
typedef __attribute__((ext_vector_type(4))) short short4v;
typedef __attribute__((ext_vector_type(4))) float f32x4;

#define MFMA16(a,b,c) __builtin_amdgcn_mfma_f32_16x16x32_bf16((a),(b),(c),0,0,0)

__device__ __forceinline__ ushort f2bf(float x) {          // RNE fp32->bf16
  unsigned u = __float_as_uint(x);
  u += 0x7FFFu + ((u >> 16) & 1u);
  return (ushort)(u >> 16);
}
__device__ __forceinline__ float bf2f(ushort b) {
  return __uint_as_float(((unsigned)b) << 16);
}
__device__ __forceinline__ float fexp2(float x) {
#if defined(__has_builtin)
#if __has_builtin(__builtin_amdgcn_exp2f)
  return __builtin_amdgcn_exp2f(x);
#else
  return exp2f(x);
#endif
#else
  return exp2f(x);
#endif
}
__device__ __forceinline__ unsigned pack_trunc(float p0, float p1) {
  return __builtin_amdgcn_perm(__float_as_uint(p1), __float_as_uint(p0), 0x07060302u);
}
// load 8 consecutive fp32, emit split-bf16 hi/lo frags
__device__ __forceinline__ void cvt8(const float* __restrict__ p, short8* hi, short8* lo) {
  float4 v0 = *(const float4*)p;
  float4 v1 = *(const float4*)(p + 4);
  float vv[8] = {v0.x, v0.y, v0.z, v0.w, v1.x, v1.y, v1.z, v1.w};
  short8 h, l;
#pragma unroll
  for (int i = 0; i < 8; ++i) {
    ushort hh = f2bf(vv[i]);
    h[i] = (short)hh;
    l[i] = (short)f2bf(vv[i] - bf2f(hh));
  }
  *hi = h; *lo = l;
}

// ======= PRE: cpb (blocks first) | fused QKV GEMM | idxP pack =======
// q/k output layout: qhl/khl[row][64] = 4 j-blocks of [hi8 | lo8] (dims j*8..j*8+8)
__launch_bounds__(256)
__global__ void pre_kernel(const float* __restrict__ x, const float* __restrict__ wq,
                           const int* __restrict__ idx,
                           const float* __restrict__ tbl, const float* __restrict__ W1,
                           const float* __restrict__ b1, const float* __restrict__ W2,
                           const float* __restrict__ b2,
                           const float* __restrict__ bias, const float* __restrict__ temp,
                           const float* __restrict__ sls, const float* __restrict__ qe,
                           ushort* __restrict__ qhl, ushort* __restrict__ khl,
                           ushort* __restrict__ vT,
                           unsigned* __restrict__ idxP, ushort* __restrict__ tabBf) {
  __shared__ __align__(16) float smem[8192];   // 32 KB union
  int blk = blockIdx.x;
  int tid = threadIdx.x;

  if (blk < CPB_BLOCKS) {
    // ---- CPB MLP, LDS-tiled ----
    float* w1b = smem;
    float* w2t = smem + 2048;
    float* part = smem + 6144;
    for (int i = tid; i < CPBH; i += 256) {
      w1b[i * 4 + 0] = W1[2 * i];
      w1b[i * 4 + 1] = W1[2 * i + 1];
      w1b[i * 4 + 2] = b1[i];
      w1b[i * 4 + 3] = 0.f;
    }
    for (int i = tid; i < CPBH * NHEADS; i += 256)
      w2t[(i & (CPBH - 1)) * NHEADS + (i >> 9)] = W2[i];
    int tl = tid & 63, jc = tid >> 6;
    int t = blk * 64 + tl;
    bool valid = t < TAB;
    float c0 = 0.f, c1 = 0.f;
    if (valid) { c0 = tbl[2 * t]; c1 = tbl[2 * t + 1]; }
    __syncthreads();
    float acc[NHEADS];
#pragma unroll
    for (int h = 0; h < NHEADS; ++h) acc[h] = 0.f;
    for (int j = jc * 128; j < jc * 128 + 128; ++j) {
      float4 wv = *(const float4*)&w1b[j * 4];
      float hid = fmaxf(fmaf(c0, wv.x, fmaf(c1, wv.y, wv.z)), 0.f);
      float4 wa = *(const float4*)&w2t[j * NHEADS];
      float4 wb = *(const float4*)&w2t[j * NHEADS + 4];
      acc[0] = fmaf(hid, wa.x, acc[0]);
      acc[1] = fmaf(hid, wa.y, acc[1]);
      acc[2] = fmaf(hid, wa.z, acc[2]);
      acc[3] = fmaf(hid, wa.w, acc[3]);
      acc[4] = fmaf(hid, wb.x, acc[4]);
      acc[5] = fmaf(hid, wb.y, acc[5]);
      acc[6] = fmaf(hid, wb.z, acc[6]);
      acc[7] = fmaf(hid, wb.w, acc[7]);
    }
#pragma unroll
    for (int h = 0; h < NHEADS; ++h) part[((size_t)jc * 64 + tl) * NHEADS + h] = acc[h];
    __syncthreads();
    if (jc == 0 && valid) {
#pragma unroll
      for (int h = 0; h < NHEADS; ++h) {
        float s = b2[h];
#pragma unroll
        for (int p = 0; p < 4; ++p) s += part[((size_t)p * 64 + tl) * NHEADS + h];
        tabBf[h * TABP + t] = f2bf(s * LOG2E);
      }
    }
  } else if (blk < CPB_BLOCKS + QKV_BLOCKS) {
    // ---- fused QKV GEMM: x and Wqkv read fp32, inline split-bf16 ----
    float (*vbuf)[65] = (float(*)[65])smem;
    int t = blk - CPB_BLOCKS;
    int n0 = (t % 12) * 64, m0 = (t / 12) * 64;
    int lane = tid & 63, w = tid >> 6;
    int g = lane >> 4, c = lane & 15;
    int mw = m0 + w * 16;
    const int K = DIMC;
    f32x4 acc[4] = {{0,0,0,0},{0,0,0,0},{0,0,0,0},{0,0,0,0}};
#pragma unroll 2
    for (int k0 = 0; k0 < K; k0 += 32) {
      short8 ah, al;
      cvt8(&x[(size_t)(mw + c) * K + k0 + g * 8], &ah, &al);
#pragma unroll
      for (int nt = 0; nt < 4; ++nt) {
        short8 bh, bl;
        cvt8(&wq[(size_t)(n0 + nt * 16 + c) * K + k0 + g * 8], &bh, &bl);
        acc[nt] = MFMA16(ah, bh, acc[nt]);
        acc[nt] = MFMA16(al, bh, acc[nt]);
        acc[nt] = MFMA16(ah, bl, acc[nt]);
      }
    }
#pragma unroll
    for (int nt = 0; nt < 4; ++nt) {
      float bv = bias[n0 + nt * 16 + c];
#pragma unroll
      for (int r = 0; r < 4; ++r) acc[nt][r] += bv;
    }

    int b = (m0 >= NSEQ) ? 1 : 0;
    int nb = m0 - b * NSEQ;
    int sect = n0 >> 8;
    int hloc = (n0 & 255) >> 5;

    if (sect < 2) {
#pragma unroll
      for (int H = 0; H < 2; ++H) {
        int head = hloc + H;
        float scale = (sect == 0) ? log1pf(expf(temp[head])) * sls[0] * LOG2E : 0.f;
#pragma unroll
        for (int r = 0; r < 4; ++r) {
          float ss = acc[2*H][r]*acc[2*H][r] + acc[2*H+1][r]*acc[2*H+1][r];
          ss += __shfl_xor(ss, 1);
          ss += __shfl_xor(ss, 2);
          ss += __shfl_xor(ss, 4);
          ss += __shfl_xor(ss, 8);
          float inv = 1.f / fmaxf(sqrtf(ss), 1e-12f);
#pragma unroll
          for (int half = 0; half < 2; ++half) {
            int d = half * 16 + c;
            float val = acc[2*H + half][r] * inv;
            if (sect == 0) val = (val + qe[head * HDIM + d]) * scale;
            vbuf[w * 16 + g * 4 + r][H * 32 + d] = val;
          }
        }
      }
      __syncthreads();
      // emit interleaved [hi8|lo8] per 8-dim block: thread = (half, head, row), 64B contiguous
      int half = tid >> 7;             // dims half*16 .. half*16+16
      int seg = tid & 127;
      int head = seg >> 6, row = seg & 63;
      const float* srcrow = &vbuf[row][head * 32 + half * 16];
      ushort out16[32];                // [hi8(j0) lo8(j0) hi8(j1) lo8(j1)]
#pragma unroll
      for (int jb = 0; jb < 2; ++jb)
#pragma unroll
        for (int i = 0; i < 8; ++i) {
          float v = srcrow[jb * 8 + i];
          ushort hh = f2bf(v);
          out16[jb * 16 + i] = hh;
          out16[jb * 16 + 8 + i] = f2bf(v - bf2f(hh));
        }
      ushort* dstp = (sect == 0) ? qhl : khl;
      size_t off = ((size_t)(b * NHEADS + hloc + head) * NSEQ + nb + row) * 64 + half * 32;
#pragma unroll
      for (int q4 = 0; q4 < 4; ++q4)
        *(int4*)&dstp[off + q4 * 8] = ((int4*)out16)[q4];
    } else {
#pragma unroll
      for (int nt = 0; nt < 4; ++nt)
#pragma unroll
        for (int r = 0; r < 4; ++r)
          vbuf[w * 16 + g * 4 + r][nt * 16 + c] = acc[nt][r];
      __syncthreads();
      int hbase = (n0 - 512) >> 5;
#pragma unroll
      for (int it = 0; it < 16; ++it) {
        int dloc = (tid >> 6) * 16 + it;
        int p = tid & 63;
        int pp = p & 31;
        int nsrc = (p & 32) + (pp & 1) * 16 + (pp >> 1);
        float v = vbuf[nsrc][dloc];
        int head = hbase + (dloc >> 5), d = dloc & 31;
        vT[((size_t)((b * NHEADS + head) * HDIM + d)) * NSEQ + nb + p] = f2bf(v);
      }
    }
  } else {
    // ---- idx pair-pack x4 ----
    int t4 = (blk - CPB_BLOCKS - QKV_BLOCKS) * 256 + tid;
    int cc4 = (t4 & 3) * 4;
    int ch = (t4 >> 2) % NCHUNK;
    int n = t4 / (4 * NCHUNK);
    int mbase = ch * 32 + cc4;
    int4 a = *(const int4*)&idx[(size_t)n * NSEQ + mbase];
    int4 b = *(const int4*)&idx[(size_t)n * NSEQ + mbase + 16];
    uint4 o;
    o.x = (unsigned)a.x | ((unsigned)b.x << 16);
    o.y = (unsigned)a.y | ((unsigned)b.y << 16);
    o.z = (unsigned)a.z | ((unsigned)b.z << 16);
    o.w = (unsigned)a.w | ((unsigned)b.w << 16);
    *(uint4*)&idxP[((size_t)n * NCHUNK + ch) * 16 + cc4] = o;
  }
}

// ------- MFMA flash attention: 2 q-tiles share K/vT, MFMA-L, interleaved q/k planes -------
__launch_bounds__(256)
__global__ void attn_kernel(const ushort* __restrict__ qhl, const ushort* __restrict__ khl,
                            const ushort* __restrict__ vT, const ushort* __restrict__ tabBf,
                            const unsigned* __restrict__ idxP,
                            float* __restrict__ pO, float* __restrict__ pL) {
  __shared__ __align__(16) ushort tbf[TABP];           // 18.1 KB
  __shared__ __align__(16) ushort pbuf[8][16 * PBS];   // 9.2 KB dual per wave
  int tid = threadIdx.x;
  int lane = tid & 63;
  int w = tid >> 6;
  int qb = blockIdx.x;                  // 0..17 : 128-q-row tile
  int by = blockIdx.y;                  // 0..63
  int s = by & 3, bh = by >> 2;
  int h = bh & (NHEADS - 1);

  const ushort* tsrc = tabBf + h * TABP;
#pragma unroll
  for (int i = 0; i < 5; ++i) {
    int off = i * 2048 + tid * 8;
    if (off < TABP) *(int4*)&tbf[off] = *(const int4*)&tsrc[off];
  }

  int g = lane >> 4, c = lane & 15;
  int q0 = qb * 128 + w * 16;
  int q1 = q0 + 64;
  size_t rowbase = (size_t)bh * NSEQ;

  // q frags: one base per tile, hi at +g*16, lo at +g*16+8
  size_t qa_ = (rowbase + q0 + c) * 64 + g * 16;
  short8 qAh = *(const short8*)&qhl[qa_];
  short8 qAl = *(const short8*)&qhl[qa_ + 8];
  size_t qb_ = (rowbase + q1 + c) * 64 + g * 16;
  short8 qBh = *(const short8*)&qhl[qb_];
  short8 qBl = *(const short8*)&qhl[qb_ + 8];
  __syncthreads();

  short one = (c == 0) ? (short)0x3F80 : (short)0;
  short8 onesB = {one, one, one, one, one, one, one, one};

  f32x4 oa0 = {0,0,0,0}, oa1 = {0,0,0,0}, ob0 = {0,0,0,0}, ob1 = {0,0,0,0};
  f32x4 la = {0,0,0,0}, lb = {0,0,0,0};
  ushort* pba = pbuf[w * 2];
  ushort* pbb = pbuf[w * 2 + 1];
  int m0 = s * MSP;

  // K loads: ONE address per chunk; hi/lo/row+16 via immediate offsets (+8, +1024 u16)
#define LOADK(MT, D0H, D0L, D1H, D1L, IA0, IA1, IA2, IA3, IB0, IB1, IB2, IB3) do { \
    const ushort* kp_ = &khl[(rowbase + (MT) + c) * 64 + g * 16];     \
    D0H = *(const short8*)kp_;                                        \
    D0L = *(const short8*)(kp_ + 8);                                  \
    D1H = *(const short8*)(kp_ + 16 * 64);                            \
    D1L = *(const short8*)(kp_ + 16 * 64 + 8);                        \
    size_t ia_ = ((size_t)(q0 + g * 4) * NCHUNK + ((MT) >> 5)) * 16 + c; \
    IA0 = idxP[ia_];                                                  \
    IA1 = idxP[ia_ + (size_t)NCHUNK * 16];                            \
    IA2 = idxP[ia_ + (size_t)2 * NCHUNK * 16];                        \
    IA3 = idxP[ia_ + (size_t)3 * NCHUNK * 16];                        \
    size_t ibx_ = ((size_t)(q1 + g * 4) * NCHUNK + ((MT) >> 5)) * 16 + c; \
    IB0 = idxP[ibx_];                                                 \
    IB1 = idxP[ibx_ + (size_t)NCHUNK * 16];                           \
    IB2 = idxP[ibx_ + (size_t)2 * NCHUNK * 16];                       \
    IB3 = idxP[ibx_ + (size_t)3 * NCHUNK * 16];                       \
  } while (0)

  short8 c0h, c0l, c1h, c1l;
  unsigned ia0, ia1, ia2, ia3, ib0, ib1, ib2, ib3;
  LOADK(m0, c0h, c0l, c1h, c1l, ia0, ia1, ia2, ia3, ib0, ib1, ib2, ib3);

  for (int mt = m0; mt < m0 + MSP; mt += 32) {
    int mtn = (mt + 32 < m0 + MSP) ? (mt + 32) : m0;
    short8 n0h, n0l, n1h, n1l;
    unsigned ja0, ja1, ja2, ja3, jb0, jb1, jb2, jb3;
    LOADK(mtn, n0h, n0l, n1h, n1l, ja0, ja1, ja2, ja3, jb0, jb1, jb2, jb3);

    f32x4 sa0 = {0,0,0,0}, sa1 = {0,0,0,0}, sb0 = {0,0,0,0}, sb1 = {0,0,0,0};
    sa0 = MFMA16(qAh, c0h, sa0);
    sb0 = MFMA16(qBh, c0h, sb0);
    sa1 = MFMA16(qAh, c1h, sa1);
    sb1 = MFMA16(qBh, c1h, sb1);
    sa0 = MFMA16(qAl, c0h, sa0);
    sb0 = MFMA16(qBl, c0h, sb0);
    sa1 = MFMA16(qAl, c1h, sa1);
    sb1 = MFMA16(qBl, c1h, sb1);
    sa0 = MFMA16(qAh, c0l, sa0);
    sb0 = MFMA16(qBh, c0l, sb0);
    sa1 = MFMA16(qAh, c1l, sa1);
    sb1 = MFMA16(qBh, c1l, sb1);

    size_t va = ((size_t)(bh * HDIM + c)) * NSEQ + mt + g * 8;
    short8 vf0 = *(const short8*)&vT[va];
    short8 vf1 = *(const short8*)&vT[va + 16 * NSEQ];

    unsigned ipa[4] = {ia0, ia1, ia2, ia3};
    unsigned ipb[4] = {ib0, ib1, ib2, ib3};
#pragma unroll
    for (int r = 0; r < 4; ++r) {
      int k0 = ipa[r] & 0xFFFF, k1 = ipa[r] >> 16;
      float pA0 = fexp2(sa0[r] + bf2f(tbf[k0]));
      float pA1 = fexp2(sa1[r] + bf2f(tbf[k1]));
      *(unsigned*)&pba[(g * 4 + r) * PBS + 2 * c] = pack_trunc(pA0, pA1);
    }
#pragma unroll
    for (int r = 0; r < 4; ++r) {
      int k0 = ipb[r] & 0xFFFF, k1 = ipb[r] >> 16;
      float pB0 = fexp2(sb0[r] + bf2f(tbf[k0]));
      float pB1 = fexp2(sb1[r] + bf2f(tbf[k1]));
      *(unsigned*)&pbb[(g * 4 + r) * PBS + 2 * c] = pack_trunc(pB0, pB1);
    }

    short4v paA = *(const short4v*)&pba[c * PBS + g * 8];
    short4v paB = *(const short4v*)&pba[c * PBS + g * 8 + 4];
    short8 pfa = __builtin_shufflevector(paA, paB, 0, 1, 2, 3, 4, 5, 6, 7);
    short4v pbA = *(const short4v*)&pbb[c * PBS + g * 8];
    short4v pbB = *(const short4v*)&pbb[c * PBS + g * 8 + 4];
    short8 pfb = __builtin_shufflevector(pbA, pbB, 0, 1, 2, 3, 4, 5, 6, 7);

    oa0 = MFMA16(pfa, vf0, oa0);
    oa1 = MFMA16(pfa, vf1, oa1);
    ob0 = MFMA16(pfb, vf0, ob0);
    ob1 = MFMA16(pfb, vf1, ob1);
    la  = MFMA16(pfa, onesB, la);
    lb  = MFMA16(pfb, onesB, lb);

    c0h = n0h; c0l = n0l; c1h = n1h; c1l = n1l;
    ia0 = ja0; ia1 = ja1; ia2 = ja2; ia3 = ja3;
    ib0 = jb0; ib1 = jb1; ib2 = jb2; ib3 = jb3;
  }
#undef LOADK

  size_t prow0 = (size_t)s * RTOT + rowbase;
#pragma unroll
  for (int r = 0; r < 4; ++r) {
    size_t pra = prow0 + q0 + g * 4 + r;
    pO[pra * HDIM + c]      = oa0[r];
    pO[pra * HDIM + 16 + c] = oa1[r];
    size_t prb = prow0 + q1 + g * 4 + r;
    pO[prb * HDIM + c]      = ob0[r];
    pO[prb * HDIM + 16 + c] = ob1[r];
    if (c == 0) { pL[pra] = la[r]; pL[prb] = lb[r]; }
  }
}

// ------- fused merge + proj GEMM (Wp read fp32, inline split) -------
#define ALD 264
__launch_bounds__(256)
__global__ void gemm_proj_fused(const float* __restrict__ pO, const float* __restrict__ pL,
                                const float* __restrict__ Wp,
                                const float* __restrict__ bias, float* __restrict__ C) {
  __shared__ __align__(16) ushort Ahs[64 * ALD];
  __shared__ __align__(16) ushort Als[64 * ALD];
  int tid = threadIdx.x;
  int m0 = blockIdx.x * 64;
  int b = (m0 >= NSEQ) ? 1 : 0;
  int nb = m0 - b * NSEQ;

  {
    int r = tid >> 2;
    int q = tid & 3;
    int n = nb + r;
#pragma unroll
    for (int h = 0; h < NHEADS; ++h) {
      size_t bhn = (size_t)(b * NHEADS + h) * NSEQ + n;
      float L = 0.f;
#pragma unroll
      for (int sp = 0; sp < SPLITS; ++sp) L += pL[(size_t)sp * RTOT + bhn];
      float inv = 1.f / L;
      float a[8] = {0.f, 0.f, 0.f, 0.f, 0.f, 0.f, 0.f, 0.f};
#pragma unroll
      for (int sp = 0; sp < SPLITS; ++sp) {
        const float* src = &pO[((size_t)sp * RTOT + bhn) * HDIM + q * 8];
        float4 v0 = *(const float4*)&src[0];
        float4 v1 = *(const float4*)&src[4];
        a[0] += v0.x; a[1] += v0.y; a[2] += v0.z; a[3] += v0.w;
        a[4] += v1.x; a[5] += v1.y; a[6] += v1.z; a[7] += v1.w;
      }
      ushort hi8[8], lo8[8];
#pragma unroll
      for (int i = 0; i < 8; ++i) {
        float v = a[i] * inv;
        ushort hh = f2bf(v);
        hi8[i] = hh;
        lo8[i] = f2bf(v - bf2f(hh));
      }
      int k = h * 32 + q * 8;
      *(int4*)&Ahs[r * ALD + k] = *(int4*)hi8;
      *(int4*)&Als[r * ALD + k] = *(int4*)lo8;
    }
  }
  __syncthreads();

  int lane = tid & 63, w = tid >> 6;
  int g = lane >> 4, c = lane & 15;
  int n0 = w * 64;
  f32x4 acc[4][4] = {};
  for (int k0 = 0; k0 < DIMC; k0 += 32) {
    short8 bfh[4], bfl[4];
#pragma unroll
    for (int nt = 0; nt < 4; ++nt)
      cvt8(&Wp[(size_t)(n0 + nt * 16 + c) * DIMC + k0 + g * 8], &bfh[nt], &bfl[nt]);
#pragma unroll
    for (int mt = 0; mt < 4; ++mt) {
      short8 ah = *(const short8*)&Ahs[(mt * 16 + c) * ALD + k0 + g * 8];
      short8 al = *(const short8*)&Als[(mt * 16 + c) * ALD + k0 + g * 8];
#pragma unroll
      for (int nt = 0; nt < 4; ++nt) {
        acc[mt][nt] = MFMA16(ah, bfh[nt], acc[mt][nt]);
        acc[mt][nt] = MFMA16(al, bfh[nt], acc[mt][nt]);
        acc[mt][nt] = MFMA16(ah, bfl[nt], acc[mt][nt]);
      }
    }
  }
#pragma unroll
  for (int nt = 0; nt < 4; ++nt) {
    float bv = bias[n0 + nt * 16 + c];
#pragma unroll
    for (int mt = 0; mt < 4; ++mt)
#pragma unroll
      for (int r = 0; r < 4; ++r)
        C[(size_t)(m0 + mt * 16 + g * 4 + r) * DIMC + n0 + nt * 16 + c] = acc[mt][nt][r] + bv;
  }
}

extern "C" void kernel_launch(void* const* d_in, const int* in_sizes, int n_in,
                              void* d_out, int out_size, void* d_ws, size_t ws_size,
                              hipStream_t stream) {
  const float* x    = (const float*)d_in[0];
  const int*   idx  = (const int*)d_in[1];
  const float* tbl  = (const float*)d_in[2];
  const float* sls  = (const float*)d_in[3];
  const float* Wqkv = (const float*)d_in[5];
  const float* bqkv = (const float*)d_in[6];
  const float* temp = (const float*)d_in[7];
  const float* qe   = (const float*)d_in[8];
  const float* Wp   = (const float*)d_in[9];
  const float* bp   = (const float*)d_in[10];
  const float* W1   = (const float*)d_in[11];
  const float* b1   = (const float*)d_in[12];
  const float* W2   = (const float*)d_in[13];
  const float* b2   = (const float*)d_in[14];

  float* ws   = (float*)d_ws;
  float* pO   = ws;                                       // 4*RTOT*HDIM = 4,718,592 f
  float* pL   = pO + (size_t)SPLITS * RTOT * HDIM;        // 147,456 f
  unsigned* idxP = (unsigned*)(pL + (size_t)SPLITS * RTOT);
  ushort* u   = (ushort*)(idxP + IDXP_ELEMS);
  ushort* qhl = u;                u += (size_t)RTOT * 64;
  ushort* khl = u;                u += (size_t)RTOT * 64;
  ushort* vT  = u;                u += (size_t)RTOT * HDIM;
  ushort* tabBf = u;              u += 73728;
  float* out  = (float*)d_out;

  pre_kernel<<<dim3(CPB_BLOCKS + QKV_BLOCKS + IDXP4_BLOCKS), dim3(256), 0, stream>>>(
      x, Wqkv, idx, tbl, W1, b1, W2, b2, bqkv, temp, sls, qe,
      qhl, khl, vT, idxP, tabBf);
  attn_kernel<<<dim3(NSEQ / 128, BB * NHEADS * SPLITS), dim3(256), 0, stream>>>(
      qhl, khl, vT, tabBf, idxP, pO, pL);
  gemm_proj_fused<<<dim3((BB * NSEQ) / 64), dim3(256), 0, stream>>>(
      pO, pL, Wp, bp, out);
}

// Round 16
// 213.986 us; speedup vs baseline: 1.1041x; 1.1041x over previous
//
#include <hip/hip_runtime.h>
#include <math.h>

#define DIMC 256
#define NHEADS 8
#define HDIM 32
#define CPBH 512
#define BB 2
#define NSEQ 2304
#define TAB 9025
#define TABP 9040                  // padded table stride
#define RTOT (BB*NHEADS*NSEQ)      // 36864
#define SPLITS 4
#define MSP (NSEQ/SPLITS)          // 576 m per split
#define PBS 36                     // pbuf row stride in u16
#define NCHUNK (NSEQ/32)           // 72
#define LOG2E 1.44269504088896340736f

#define NWQ (3*DIMC*DIMC)          // 196,608
#define IDXP_ELEMS    (NSEQ * NCHUNK * 16)             // 2,654,208
#define IDXP4_BLOCKS  (IDXP_ELEMS / 1024)              // 2592
#define CPB_BLOCKS    ((TAB + 63) / 64)                // 142
#define QKV_BLOCKS    (12 * 72)                        // 864

typedef unsigned short ushort;
typedef __attribute__((ext_vector_type(8))) short short8;
typedef __attribute__((ext_vector_type(4))) short short4v;
typedef __attribute__((ext_vector_type(4))) float f32x4;

#define MFMA16(a,b,c) __builtin_amdgcn_mfma_f32_16x16x32_bf16((a),(b),(c),0,0,0)

__device__ __forceinline__ ushort f2bf(float x) {          // RNE fp32->bf16
  unsigned u = __float_as_uint(x);
  u += 0x7FFFu + ((u >> 16) & 1u);
  return (ushort)(u >> 16);
}
__device__ __forceinline__ float bf2f(ushort b) {
  return __uint_as_float(((unsigned)b) << 16);
}
__device__ __forceinline__ float fexp2(float x) {
#if defined(__has_builtin)
#if __has_builtin(__builtin_amdgcn_exp2f)
  return __builtin_amdgcn_exp2f(x);
#else
  return exp2f(x);
#endif
#else
  return exp2f(x);
#endif
}
__device__ __forceinline__ unsigned pack_trunc(float p0, float p1) {
  return __builtin_amdgcn_perm(__float_as_uint(p1), __float_as_uint(p0), 0x07060302u);
}
// load 8 consecutive fp32, emit split-bf16 hi/lo frags
__device__ __forceinline__ void cvt8(const float* __restrict__ p, short8* hi, short8* lo) {
  float4 v0 = *(const float4*)p;
  float4 v1 = *(const float4*)(p + 4);
  float vv[8] = {v0.x, v0.y, v0.z, v0.w, v1.x, v1.y, v1.z, v1.w};
  short8 h, l;
#pragma unroll
  for (int i = 0; i < 8; ++i) {
    ushort hh = f2bf(vv[i]);
    h[i] = (short)hh;
    l[i] = (short)f2bf(vv[i] - bf2f(hh));
  }
  *hi = h; *lo = l;
}

// ======= PRE: cpb (blocks first) | fused QKV GEMM (inline weight cvt) | idxP pack =======
__launch_bounds__(256)
__global__ void pre_kernel(const float* __restrict__ x, const float* __restrict__ wq,
                           const int* __restrict__ idx,
                           const float* __restrict__ tbl, const float* __restrict__ W1,
                           const float* __restrict__ b1, const float* __restrict__ W2,
                           const float* __restrict__ b2,
                           const float* __restrict__ bias, const float* __restrict__ temp,
                           const float* __restrict__ sls, const float* __restrict__ qe,
                           ushort* __restrict__ qhi, ushort* __restrict__ qlo,
                           ushort* __restrict__ khi, ushort* __restrict__ klo,
                           ushort* __restrict__ vT,
                           unsigned* __restrict__ idxP, ushort* __restrict__ tabBf) {
  __shared__ __align__(16) float smem[8192];   // 32 KB union
  int blk = blockIdx.x;
  int tid = threadIdx.x;

  if (blk < CPB_BLOCKS) {
    // ---- CPB MLP, LDS-tiled ----
    float* w1b = smem;                  // 2048 f
    float* w2t = smem + 2048;           // 4096 f
    float* part = smem + 6144;          // 2048 f
    for (int i = tid; i < CPBH; i += 256) {
      w1b[i * 4 + 0] = W1[2 * i];
      w1b[i * 4 + 1] = W1[2 * i + 1];
      w1b[i * 4 + 2] = b1[i];
      w1b[i * 4 + 3] = 0.f;
    }
    for (int i = tid; i < CPBH * NHEADS; i += 256)
      w2t[(i & (CPBH - 1)) * NHEADS + (i >> 9)] = W2[i];
    int tl = tid & 63, jc = tid >> 6;
    int t = blk * 64 + tl;
    bool valid = t < TAB;
    float c0 = 0.f, c1 = 0.f;
    if (valid) { c0 = tbl[2 * t]; c1 = tbl[2 * t + 1]; }
    __syncthreads();
    float acc[NHEADS];
#pragma unroll
    for (int h = 0; h < NHEADS; ++h) acc[h] = 0.f;
    for (int j = jc * 128; j < jc * 128 + 128; ++j) {
      float4 wv = *(const float4*)&w1b[j * 4];
      float hid = fmaxf(fmaf(c0, wv.x, fmaf(c1, wv.y, wv.z)), 0.f);
      float4 wa = *(const float4*)&w2t[j * NHEADS];
      float4 wb = *(const float4*)&w2t[j * NHEADS + 4];
      acc[0] = fmaf(hid, wa.x, acc[0]);
      acc[1] = fmaf(hid, wa.y, acc[1]);
      acc[2] = fmaf(hid, wa.z, acc[2]);
      acc[3] = fmaf(hid, wa.w, acc[3]);
      acc[4] = fmaf(hid, wb.x, acc[4]);
      acc[5] = fmaf(hid, wb.y, acc[5]);
      acc[6] = fmaf(hid, wb.z, acc[6]);
      acc[7] = fmaf(hid, wb.w, acc[7]);
    }
#pragma unroll
    for (int h = 0; h < NHEADS; ++h) part[((size_t)jc * 64 + tl) * NHEADS + h] = acc[h];
    __syncthreads();
    if (jc == 0 && valid) {
#pragma unroll
      for (int h = 0; h < NHEADS; ++h) {
        float s = b2[h];
#pragma unroll
        for (int p = 0; p < 4; ++p) s += part[((size_t)p * 64 + tl) * NHEADS + h];
        tabBf[h * TABP + t] = f2bf(s * LOG2E);
      }
    }
  } else if (blk < CPB_BLOCKS + QKV_BLOCKS) {
    // ---- fused QKV GEMM: x and Wqkv read fp32, inline split-bf16 ----
    float (*vbuf)[65] = (float(*)[65])smem;
    int t = blk - CPB_BLOCKS;
    int n0 = (t % 12) * 64, m0 = (t / 12) * 64;
    int lane = tid & 63, w = tid >> 6;
    int g = lane >> 4, c = lane & 15;
    int mw = m0 + w * 16;
    const int K = DIMC;
    f32x4 acc[4] = {{0,0,0,0},{0,0,0,0},{0,0,0,0},{0,0,0,0}};
#pragma unroll 2
    for (int k0 = 0; k0 < K; k0 += 32) {
      short8 ah, al;
      cvt8(&x[(size_t)(mw + c) * K + k0 + g * 8], &ah, &al);
#pragma unroll
      for (int nt = 0; nt < 4; ++nt) {
        short8 bh, bl;
        cvt8(&wq[(size_t)(n0 + nt * 16 + c) * K + k0 + g * 8], &bh, &bl);
        acc[nt] = MFMA16(ah, bh, acc[nt]);
        acc[nt] = MFMA16(al, bh, acc[nt]);
        acc[nt] = MFMA16(ah, bl, acc[nt]);
      }
    }
#pragma unroll
    for (int nt = 0; nt < 4; ++nt) {
      float bv = bias[n0 + nt * 16 + c];
#pragma unroll
      for (int r = 0; r < 4; ++r) acc[nt][r] += bv;
    }

    int b = (m0 >= NSEQ) ? 1 : 0;
    int nb = m0 - b * NSEQ;
    int sect = n0 >> 8;
    int hloc = (n0 & 255) >> 5;

    if (sect < 2) {
#pragma unroll
      for (int H = 0; H < 2; ++H) {
        int head = hloc + H;
        float scale = (sect == 0) ? log1pf(expf(temp[head])) * sls[0] * LOG2E : 0.f;
#pragma unroll
        for (int r = 0; r < 4; ++r) {
          float ss = acc[2*H][r]*acc[2*H][r] + acc[2*H+1][r]*acc[2*H+1][r];
          ss += __shfl_xor(ss, 1);
          ss += __shfl_xor(ss, 2);
          ss += __shfl_xor(ss, 4);
          ss += __shfl_xor(ss, 8);
          float inv = 1.f / fmaxf(sqrtf(ss), 1e-12f);
#pragma unroll
          for (int half = 0; half < 2; ++half) {
            int d = half * 16 + c;
            float val = acc[2*H + half][r] * inv;
            if (sect == 0) val = (val + qe[head * HDIM + d]) * scale;
            vbuf[w * 16 + g * 4 + r][H * 32 + d] = val;
          }
        }
      }
      __syncthreads();
      int plane = tid >> 7;
      int seg = tid & 127;
      int head = seg >> 6, row = seg & 63;
      const float* srcrow = &vbuf[row][head * 32];
      ushort out16[32];
#pragma unroll
      for (int i = 0; i < 32; ++i) {
        float v = srcrow[i];
        ushort hh = f2bf(v);
        out16[i] = plane ? f2bf(v - bf2f(hh)) : hh;
      }
      ushort* dstp = plane ? (sect == 0 ? qlo : klo) : (sect == 0 ? qhi : khi);
      size_t off = ((size_t)(b * NHEADS + hloc + head) * NSEQ + nb + row) * HDIM;
#pragma unroll
      for (int q4 = 0; q4 < 4; ++q4)
        *(int4*)&dstp[off + q4 * 8] = ((int4*)out16)[q4];
    } else {
#pragma unroll
      for (int nt = 0; nt < 4; ++nt)
#pragma unroll
        for (int r = 0; r < 4; ++r)
          vbuf[w * 16 + g * 4 + r][nt * 16 + c] = acc[nt][r];
      __syncthreads();
      int hbase = (n0 - 512) >> 5;
#pragma unroll
      for (int it = 0; it < 16; ++it) {
        int dloc = (tid >> 6) * 16 + it;
        int p = tid & 63;
        int pp = p & 31;
        int nsrc = (p & 32) + (pp & 1) * 16 + (pp >> 1);
        float v = vbuf[nsrc][dloc];
        int head = hbase + (dloc >> 5), d = dloc & 31;
        vT[((size_t)((b * NHEADS + head) * HDIM + d)) * NSEQ + nb + p] = f2bf(v);
      }
    }
  } else {
    // ---- idx pair-pack x4 ----
    int t4 = (blk - CPB_BLOCKS - QKV_BLOCKS) * 256 + tid;
    int cc4 = (t4 & 3) * 4;
    int ch = (t4 >> 2) % NCHUNK;
    int n = t4 / (4 * NCHUNK);
    int mbase = ch * 32 + cc4;
    int4 a = *(const int4*)&idx[(size_t)n * NSEQ + mbase];
    int4 b = *(const int4*)&idx[(size_t)n * NSEQ + mbase + 16];
    uint4 o;
    o.x = (unsigned)a.x | ((unsigned)b.x << 16);
    o.y = (unsigned)a.y | ((unsigned)b.y << 16);
    o.z = (unsigned)a.z | ((unsigned)b.z << 16);
    o.w = (unsigned)a.w | ((unsigned)b.w << 16);
    *(uint4*)&idxP[((size_t)n * NCHUNK + ch) * 16 + cc4] = o;
  }
}

// ------- MFMA flash attention: 2 q-tiles share K/vT, MFMA-L, SPLITS=4 -------
__launch_bounds__(256)
__global__ void attn_kernel(const ushort* __restrict__ qhi, const ushort* __restrict__ qlo,
                            const ushort* __restrict__ khi, const ushort* __restrict__ klo,
                            const ushort* __restrict__ vT, const ushort* __restrict__ tabBf,
                            const unsigned* __restrict__ idxP,
                            float* __restrict__ pO, float* __restrict__ pL) {
  __shared__ ushort tbf[10240];                        // 20 KB
  __shared__ __align__(16) ushort pbuf[8][16 * PBS];   // 9.2 KB
  int tid = threadIdx.x;
  int lane = tid & 63;
  int w = tid >> 6;
  int qb = blockIdx.x;                  // 0..17 : 128-q-row tile
  int by = blockIdx.y;                  // 0..63
  int s = by & 3, bh = by >> 2;
  int h = bh & (NHEADS - 1);

  const ushort* tsrc = tabBf + h * TABP;
#pragma unroll
  for (int i = 0; i < 5; ++i) {
    int off = i * 2048 + tid * 8;
    *(int4*)&tbf[off] = *(const int4*)&tsrc[off];
  }

  int g = lane >> 4, c = lane & 15;
  int q0 = qb * 128 + w * 16;
  int q1 = q0 + 64;
  size_t rowbase = (size_t)bh * NSEQ;

  short8 qAh = *(const short8*)&qhi[(rowbase + q0 + c) * HDIM + g * 8];
  short8 qAl = *(const short8*)&qlo[(rowbase + q0 + c) * HDIM + g * 8];
  short8 qBh = *(const short8*)&qhi[(rowbase + q1 + c) * HDIM + g * 8];
  short8 qBl = *(const short8*)&qlo[(rowbase + q1 + c) * HDIM + g * 8];
  __syncthreads();

  short one = (c == 0) ? (short)0x3F80 : (short)0;
  short8 onesB = {one, one, one, one, one, one, one, one};

  f32x4 oa0 = {0,0,0,0}, oa1 = {0,0,0,0}, ob0 = {0,0,0,0}, ob1 = {0,0,0,0};
  f32x4 la = {0,0,0,0}, lb = {0,0,0,0};
  ushort* pba = pbuf[w * 2];
  ushort* pbb = pbuf[w * 2 + 1];
  int m0 = s * MSP;

#define LOADK(MT, D0H, D0L, D1H, D1L, IA0, IA1, IA2, IA3, IB0, IB1, IB2, IB3) do { \
    size_t ra_ = (rowbase + (MT) + c) * HDIM + g * 8;                 \
    D0H = *(const short8*)&khi[ra_];                                  \
    D0L = *(const short8*)&klo[ra_];                                  \
    D1H = *(const short8*)&khi[ra_ + 16 * HDIM];                      \
    D1L = *(const short8*)&klo[ra_ + 16 * HDIM];                      \
    size_t ia_ = ((size_t)(q0 + g * 4) * NCHUNK + ((MT) >> 5)) * 16 + c; \
    IA0 = idxP[ia_];                                                  \
    IA1 = idxP[ia_ + (size_t)NCHUNK * 16];                            \
    IA2 = idxP[ia_ + (size_t)2 * NCHUNK * 16];                        \
    IA3 = idxP[ia_ + (size_t)3 * NCHUNK * 16];                        \
    size_t ibx_ = ((size_t)(q1 + g * 4) * NCHUNK + ((MT) >> 5)) * 16 + c; \
    IB0 = idxP[ibx_];                                                 \
    IB1 = idxP[ibx_ + (size_t)NCHUNK * 16];                           \
    IB2 = idxP[ibx_ + (size_t)2 * NCHUNK * 16];                       \
    IB3 = idxP[ibx_ + (size_t)3 * NCHUNK * 16];                       \
  } while (0)

  short8 c0h, c0l, c1h, c1l;
  unsigned ia0, ia1, ia2, ia3, ib0, ib1, ib2, ib3;
  LOADK(m0, c0h, c0l, c1h, c1l, ia0, ia1, ia2, ia3, ib0, ib1, ib2, ib3);

  for (int mt = m0; mt < m0 + MSP; mt += 32) {
    int mtn = (mt + 32 < m0 + MSP) ? (mt + 32) : m0;
    short8 n0h, n0l, n1h, n1l;
    unsigned ja0, ja1, ja2, ja3, jb0, jb1, jb2, jb3;
    LOADK(mtn, n0h, n0l, n1h, n1l, ja0, ja1, ja2, ja3, jb0, jb1, jb2, jb3);

    f32x4 sa0 = {0,0,0,0}, sa1 = {0,0,0,0}, sb0 = {0,0,0,0}, sb1 = {0,0,0,0};
    sa0 = MFMA16(qAh, c0h, sa0);
    sb0 = MFMA16(qBh, c0h, sb0);
    sa1 = MFMA16(qAh, c1h, sa1);
    sb1 = MFMA16(qBh, c1h, sb1);
    sa0 = MFMA16(qAl, c0h, sa0);
    sb0 = MFMA16(qBl, c0h, sb0);
    sa1 = MFMA16(qAl, c1h, sa1);
    sb1 = MFMA16(qBl, c1h, sb1);
    sa0 = MFMA16(qAh, c0l, sa0);
    sb0 = MFMA16(qBh, c0l, sb0);
    sa1 = MFMA16(qAh, c1l, sa1);
    sb1 = MFMA16(qBh, c1l, sb1);

    size_t va = ((size_t)(bh * HDIM + c)) * NSEQ + mt + g * 8;
    short8 vf0 = *(const short8*)&vT[va];
    short8 vf1 = *(const short8*)&vT[va + 16 * NSEQ];

    unsigned ipa[4] = {ia0, ia1, ia2, ia3};
    unsigned ipb[4] = {ib0, ib1, ib2, ib3};
#pragma unroll
    for (int r = 0; r < 4; ++r) {
      int k0 = ipa[r] & 0xFFFF, k1 = ipa[r] >> 16;
      float pA0 = fexp2(sa0[r] + bf2f(tbf[k0]));
      float pA1 = fexp2(sa1[r] + bf2f(tbf[k1]));
      *(unsigned*)&pba[(g * 4 + r) * PBS + 2 * c] = pack_trunc(pA0, pA1);
    }
#pragma unroll
    for (int r = 0; r < 4; ++r) {
      int k0 = ipb[r] & 0xFFFF, k1 = ipb[r] >> 16;
      float pB0 = fexp2(sb0[r] + bf2f(tbf[k0]));
      float pB1 = fexp2(sb1[r] + bf2f(tbf[k1]));
      *(unsigned*)&pbb[(g * 4 + r) * PBS + 2 * c] = pack_trunc(pB0, pB1);
    }

    short4v paA = *(const short4v*)&pba[c * PBS + g * 8];
    short4v paB = *(const short4v*)&pba[c * PBS + g * 8 + 4];
    short8 pfa = __builtin_shufflevector(paA, paB, 0, 1, 2, 3, 4, 5, 6, 7);
    short4v pbA = *(const short4v*)&pbb[c * PBS + g * 8];
    short4v pbB = *(const short4v*)&pbb[c * PBS + g * 8 + 4];
    short8 pfb = __builtin_shufflevector(pbA, pbB, 0, 1, 2, 3, 4, 5, 6, 7);

    oa0 = MFMA16(pfa, vf0, oa0);
    oa1 = MFMA16(pfa, vf1, oa1);
    ob0 = MFMA16(pfb, vf0, ob0);
    ob1 = MFMA16(pfb, vf1, ob1);
    la  = MFMA16(pfa, onesB, la);
    lb  = MFMA16(pfb, onesB, lb);

    c0h = n0h; c0l = n0l; c1h = n1h; c1l = n1l;
    ia0 = ja0; ia1 = ja1; ia2 = ja2; ia3 = ja3;
    ib0 = jb0; ib1 = jb1; ib2 = jb2; ib3 = jb3;
  }
#undef LOADK

  size_t prow0 = (size_t)s * RTOT + rowbase;
#pragma unroll
  for (int r = 0; r < 4; ++r) {
    size_t pra = prow0 + q0 + g * 4 + r;
    pO[pra * HDIM + c]      = oa0[r];
    pO[pra * HDIM + 16 + c] = oa1[r];
    size_t prb = prow0 + q1 + g * 4 + r;
    pO[prb * HDIM + c]      = ob0[r];
    pO[prb * HDIM + 16 + c] = ob1[r];
    if (c == 0) { pL[pra] = la[r]; pL[prb] = lb[r]; }
  }
}

// ------- fused merge + proj GEMM (Wp read fp32, inline split) -------
#define ALD 264
__launch_bounds__(256)
__global__ void gemm_proj_fused(const float* __restrict__ pO, const float* __restrict__ pL,
                                const float* __restrict__ Wp,
                                const float* __restrict__ bias, float* __restrict__ C) {
  __shared__ __align__(16) ushort Ahs[64 * ALD];
  __shared__ __align__(16) ushort Als[64 * ALD];
  int tid = threadIdx.x;
  int m0 = blockIdx.x * 64;
  int b = (m0 >= NSEQ) ? 1 : 0;
  int nb = m0 - b * NSEQ;

  {
    int r = tid >> 2;
    int q = tid & 3;
    int n = nb + r;
#pragma unroll
    for (int h = 0; h < NHEADS; ++h) {
      size_t bhn = (size_t)(b * NHEADS + h) * NSEQ + n;
      float L = 0.f;
#pragma unroll
      for (int sp = 0; sp < SPLITS; ++sp) L += pL[(size_t)sp * RTOT + bhn];
      float inv = 1.f / L;
      float a[8] = {0.f, 0.f, 0.f, 0.f, 0.f, 0.f, 0.f, 0.f};
#pragma unroll
      for (int sp = 0; sp < SPLITS; ++sp) {
        const float* src = &pO[((size_t)sp * RTOT + bhn) * HDIM + q * 8];
        float4 v0 = *(const float4*)&src[0];
        float4 v1 = *(const float4*)&src[4];
        a[0] += v0.x; a[1] += v0.y; a[2] += v0.z; a[3] += v0.w;
        a[4] += v1.x; a[5] += v1.y; a[6] += v1.z; a[7] += v1.w;
      }
      ushort hi8[8], lo8[8];
#pragma unroll
      for (int i = 0; i < 8; ++i) {
        float v = a[i] * inv;
        ushort hh = f2bf(v);
        hi8[i] = hh;
        lo8[i] = f2bf(v - bf2f(hh));
      }
      int k = h * 32 + q * 8;
      *(int4*)&Ahs[r * ALD + k] = *(int4*)hi8;
      *(int4*)&Als[r * ALD + k] = *(int4*)lo8;
    }
  }
  __syncthreads();

  int lane = tid & 63, w = tid >> 6;
  int g = lane >> 4, c = lane & 15;
  int n0 = w * 64;
  f32x4 acc[4][4] = {};
  for (int k0 = 0; k0 < DIMC; k0 += 32) {
    short8 bfh[4], bfl[4];
#pragma unroll
    for (int nt = 0; nt < 4; ++nt)
      cvt8(&Wp[(size_t)(n0 + nt * 16 + c) * DIMC + k0 + g * 8], &bfh[nt], &bfl[nt]);
#pragma unroll
    for (int mt = 0; mt < 4; ++mt) {
      short8 ah = *(const short8*)&Ahs[(mt * 16 + c) * ALD + k0 + g * 8];
      short8 al = *(const short8*)&Als[(mt * 16 + c) * ALD + k0 + g * 8];
#pragma unroll
      for (int nt = 0; nt < 4; ++nt) {
        acc[mt][nt] = MFMA16(ah, bfh[nt], acc[mt][nt]);
        acc[mt][nt] = MFMA16(al, bfh[nt], acc[mt][nt]);
        acc[mt][nt] = MFMA16(ah, bfl[nt], acc[mt][nt]);
      }
    }
  }
#pragma unroll
  for (int nt = 0; nt < 4; ++nt) {
    float bv = bias[n0 + nt * 16 + c];
#pragma unroll
    for (int mt = 0; mt < 4; ++mt)
#pragma unroll
      for (int r = 0; r < 4; ++r)
        C[(size_t)(m0 + mt * 16 + g * 4 + r) * DIMC + n0 + nt * 16 + c] = acc[mt][nt][r] + bv;
  }
}

extern "C" void kernel_launch(void* const* d_in, const int* in_sizes, int n_in,
                              void* d_out, int out_size, void* d_ws, size_t ws_size,
                              hipStream_t stream) {
  const float* x    = (const float*)d_in[0];
  const int*   idx  = (const int*)d_in[1];
  const float* tbl  = (const float*)d_in[2];
  const float* sls  = (const float*)d_in[3];
  const float* Wqkv = (const float*)d_in[5];
  const float* bqkv = (const float*)d_in[6];
  const float* temp = (const float*)d_in[7];
  const float* qe   = (const float*)d_in[8];
  const float* Wp   = (const float*)d_in[9];
  const float* bp   = (const float*)d_in[10];
  const float* W1   = (const float*)d_in[11];
  const float* b1   = (const float*)d_in[12];
  const float* W2   = (const float*)d_in[13];
  const float* b2   = (const float*)d_in[14];

  float* ws   = (float*)d_ws;
  float* pO   = ws;                                       // 4*RTOT*HDIM = 4,718,592 f
  float* pL   = pO + (size_t)SPLITS * RTOT * HDIM;        // 147,456 f
  unsigned* idxP = (unsigned*)(pL + (size_t)SPLITS * RTOT);
  ushort* u   = (ushort*)(idxP + IDXP_ELEMS);
  ushort* qhi = u;                u += (size_t)RTOT * HDIM;
  ushort* qlo = u;                u += (size_t)RTOT * HDIM;
  ushort* khi = u;                u += (size_t)RTOT * HDIM;
  ushort* klo = u;                u += (size_t)RTOT * HDIM;
  ushort* vT  = u;                u += (size_t)RTOT * HDIM;
  ushort* tabBf = u;              u += 73728;
  float* out  = (float*)d_out;

  pre_kernel<<<dim3(CPB_BLOCKS + QKV_BLOCKS + IDXP4_BLOCKS), dim3(256), 0, stream>>>(
      x, Wqkv, idx, tbl, W1, b1, W2, b2, bqkv, temp, sls, qe,
      qhi, qlo, khi, klo, vT, idxP, tabBf);
  attn_kernel<<<dim3(NSEQ / 128, BB * NHEADS * SPLITS), dim3(256), 0, stream>>>(
      qhi, qlo, khi, klo, vT, tabBf, idxP, pO, pL);
  gemm_proj_fused<<<dim3((BB * NSEQ) / 64), dim3(256), 0, stream>>>(
      pO, pL, Wp, bp, out);
}